// Round 5
// baseline (122.770 us; speedup 1.0000x reference)
//
#include <hip/hip_runtime.h>
#include <math.h>
#include <stdint.h>

#define NB 4
#define LQ 768
#define NH 8
#define NE 64
#define ND 192   // 3*E augmented feature dim
#define TEMP 0.125f

typedef _Float16 f16;
typedef __attribute__((ext_vector_type(8))) _Float16 f16x8;
typedef __attribute__((ext_vector_type(4))) float f32x4;

// Async global->LDS 16B: HW writes lds_base + lane*16. lds_base wave-uniform.
__device__ __forceinline__ void stage16(f16* lds_base, const f16* g, int lane) {
#if __has_builtin(__builtin_amdgcn_global_load_lds)
    __builtin_amdgcn_global_load_lds(
        (const __attribute__((address_space(1))) uint32_t*)g,
        (__attribute__((address_space(3))) uint32_t*)lds_base, 16, 0, 0);
#else
    *(uint4*)((char*)lds_base + lane * 16) = *(const uint4*)g;
#endif
}

// ---------------- fused prep (blocks 0..767) + V transpose (768..1151) ----------------
__global__ __launch_bounds__(256) void sinattn_prepvt(
    const float* __restrict__ Q, const float* __restrict__ K,
    const float* __restrict__ V,
    const float* __restrict__ freqs, const float* __restrict__ offsets,
    const float* __restrict__ gains, const float* __restrict__ gate,
    f16* __restrict__ Qf, f16* __restrict__ Kf, f16* __restrict__ Vt)
{
    if (blockIdx.x < 768) {
        // ---- prep: augmented f16 Q'/K', 8 elems/thread ----
        int idx = blockIdx.x * 256 + threadIdx.x;   // ((n*L+l)*8 + h)*8 + eg
        int eg = idx & 7, e0 = eg << 3;
        int h  = (idx >> 3) & 7;
        int t  = idx >> 6;                          // n*L + l
        int l  = t % LQ;
        int n  = t / LQ;
        int nh = (n << 3) | h;
        int he = (h << 6) | e0;

        const float* qp = Q + (size_t)idx * 8;
        const float* kp = K + (size_t)idx * 8;
        float4 q0 = *(const float4*)qp, q1 = *(const float4*)(qp + 4);
        float4 k0 = *(const float4*)kp, k1 = *(const float4*)(kp + 4);
        float qv[8] = {q0.x,q0.y,q0.z,q0.w, q1.x,q1.y,q1.z,q1.w};
        float kv[8] = {k0.x,k0.y,k0.z,k0.w, k1.x,k1.y,k1.z,k1.w};

        float4 fA = *(const float4*)(freqs   + he), fB = *(const float4*)(freqs   + he + 4);
        float4 oA = *(const float4*)(offsets + he), oB = *(const float4*)(offsets + he + 4);
        float4 gA = *(const float4*)(gains   + he), gB = *(const float4*)(gains   + he + 4);
        float4 tA = *(const float4*)(gate    + he), tB = *(const float4*)(gate    + he + 4);
        float fv[8] = {fA.x,fA.y,fA.z,fA.w, fB.x,fB.y,fB.z,fB.w};
        float ov[8] = {oA.x,oA.y,oA.z,oA.w, oB.x,oB.y,oB.z,oB.w};
        float gv[8] = {gA.x,gA.y,gA.z,gA.w, gB.x,gB.y,gB.z,gB.w};
        float tv[8] = {tA.x,tA.y,tA.z,tA.w, tB.x,tB.y,tB.z,tB.w};

        f16x8 oq0, oq1, oq2, ok0, ok1, ok2;
        float lf = (float)l;
        #pragma unroll
        for (int j = 0; j < 8; ++j) {
            float f  = 0.5f / (1.0f + __expf(-fv[j]));
            float gn = gv[j];
            float sp = (gn > 15.0f) ? gn : __logf(1.0f + __expf(gn));
            float gt = tv[j];
            float a  = (1.0f - gt) * sp * sp;
            float fh = __uint_as_float(__float_as_uint(f) & 0xFFFFF000u);
            float fl = f - fh;
            float t0 = lf * fh;
            float tr = t0 - floorf(t0);
            tr = __builtin_fmaf(lf, fl, tr);
            float pk = 6.28318530717958647f * tr;
            float pq = pk + ov[j];
            float sq = __sinf(pq), cq = __cosf(pq);
            float sk = __sinf(pk), ck = __cosf(pk);
            oq0[j] = (f16)(qv[j] * a * cq);
            oq1[j] = (f16)(qv[j] * a * sq);
            oq2[j] = (f16)(qv[j] * gt);
            ok0[j] = (f16)(kv[j] * ck);
            ok1[j] = (f16)(kv[j] * sk);
            ok2[j] = (f16)(kv[j]);
        }
        size_t base = ((size_t)nh * LQ + l) * ND + e0;
        *(f16x8*)(Qf + base)          = oq0;
        *(f16x8*)(Qf + base + NE)     = oq1;
        *(f16x8*)(Qf + base + 2*NE)   = oq2;
        *(f16x8*)(Kf + base)          = ok0;
        *(f16x8*)(Kf + base + NE)     = ok1;
        *(f16x8*)(Kf + base + 2*NE)   = ok2;
    } else {
        // ---- V transpose: [n][s][h][e] fp32 -> Vt[nh][e][s] f16 ----
        __shared__ f16 tile[64][72];
        int b = blockIdx.x - 768;
        int st = b % 12, nh = b / 12;
        int n = nh >> 3, h = nh & 7;
        int s0 = st * 64;
        int tid = threadIdx.x;

        int sl = tid >> 2, e0 = (tid & 3) << 4;
        const float4* vp = (const float4*)(V + ((size_t)(n * LQ + s0 + sl) * NH + h) * NE + e0);
        float4 a0 = vp[0], a1 = vp[1], a2 = vp[2], a3 = vp[3];
        float vv[16] = { a0.x,a0.y,a0.z,a0.w, a1.x,a1.y,a1.z,a1.w,
                         a2.x,a2.y,a2.z,a2.w, a3.x,a3.y,a3.z,a3.w };
        #pragma unroll
        for (int j = 0; j < 16; ++j) tile[e0 + j][sl] = (f16)vv[j];
        __syncthreads();

        int er = tid >> 2, sc = tid & 3;
        f16* op = Vt + ((size_t)nh * NE + er) * LQ + s0 + sc * 16;
        *(uint4*)op       = *(const uint4*)&tile[er][sc * 16];
        *(uint4*)(op + 8) = *(const uint4*)&tile[er][sc * 16 + 8];
    }
}

// ---------------- split-K flash: each block does 6 of 12 K-chunks ----------------
// grid 768 = 32 nh x 12 q-tiles x 2 halves -> exactly 3 blocks/CU (2 LDS-resident,
// pipelined refill). bid&31 = nh keeps XCD locality (bid%8 invariant).
// Emits unnormalized O + per-row (m, l) for the merge kernel.
__global__ __launch_bounds__(256, 2) void sinattn_flash(
    const f16* __restrict__ Qf, const f16* __restrict__ Kf, const f16* __restrict__ Vt,
    const float* __restrict__ mask, const float* __restrict__ keylen,
    float* __restrict__ Op, float* __restrict__ Mp, float* __restrict__ Lp)
{
    __shared__ __attribute__((aligned(16))) f16 sK[2][64 * 24 * 8];  // 24 KB each
    __shared__ __attribute__((aligned(16))) f16 sV[2][64 * 8 * 8];   // 8 KB each
    __shared__ __attribute__((aligned(16))) f16 sP[4][16 * 72];

    int tid  = threadIdx.x;
    int wv   = tid >> 6;
    int wvu  = __builtin_amdgcn_readfirstlane(wv);   // provably wave-uniform
    int lane = tid & 63;
    int grp  = lane >> 4;
    int r16  = lane & 15;
    int swz  = r16 & 7;

    int bid  = blockIdx.x;
    int nh   = bid & 31;
    int rr2  = bid >> 5;       // 0..23
    int lt   = rr2 >> 1;       // 0..11
    int half = rr2 & 1;
    int n    = nh >> 3;
    int l0   = lt * 64;
    int c0   = half * 6;

    // Q fragments (A-layout) from global, live whole kernel
    f16x8 qf[6];
    {
        size_t rbase = ((size_t)nh * LQ + l0 + wv * 16 + r16) * ND + grp * 8;
        #pragma unroll
        for (int d0 = 0; d0 < 6; ++d0)
            qf[d0] = *(const f16x8*)(Qf + rbase + d0 * 32);
    }

    // per-lane swizzled global offsets for staging
    int goffK[6], goffV[2];
    #pragma unroll
    for (int i = 0; i < 6; ++i) {
        int p = i * 256 + wv * 64 + lane;
        int r = p / 24, c = p - r * 24;
        int cl = (c & ~7) | ((c & 7) ^ (r & 7));
        goffK[i] = r * ND + cl * 8;
    }
    #pragma unroll
    for (int i = 0; i < 2; ++i) {
        int p = i * 256 + wv * 64 + lane;
        int r = p >> 3, c = p & 7;
        goffV[i] = r * LQ + (c ^ (r & 7)) * 8;
    }
    const f16* Kb = Kf + (size_t)nh * LQ * ND;
    const f16* Vb = Vt + (size_t)nh * NE * LQ;

    // issue first chunk (c0; c0&1==0 so buffer 0)
    {
        const f16* kg = Kb + c0 * 64 * ND;
        const f16* vg = Vb + c0 * 64;
        #pragma unroll
        for (int i = 0; i < 6; ++i)
            stage16(&sK[0][(i * 256 + wvu * 64) * 8], kg + goffK[i], lane);
        #pragma unroll
        for (int i = 0; i < 2; ++i)
            stage16(&sV[0][(i * 256 + wvu * 64) * 8], vg + goffV[i], lane);
    }

    float m_i[4], l_i[4];
    f32x4 O[4];
    #pragma unroll
    for (int rr = 0; rr < 4; ++rr) { m_i[rr] = -INFINITY; l_i[rr] = 0.f; }
    #pragma unroll
    for (int tt = 0; tt < 4; ++tt)
        #pragma unroll
        for (int rr = 0; rr < 4; ++rr) O[tt][rr] = 0.f;

    for (int c = c0; c < c0 + 6; ++c) {
        int cur = c & 1;
        int s0  = c * 64;
        __syncthreads();   // staging for this chunk landed; prev reads done

        if (c < c0 + 5) {  // prefetch next chunk; in flight during compute
            const f16* kg = Kb + (s0 + 64) * ND;
            const f16* vg = Vb + (s0 + 64);
            #pragma unroll
            for (int i = 0; i < 6; ++i)
                stage16(&sK[cur ^ 1][(i * 256 + wvu * 64) * 8], kg + goffK[i], lane);
            #pragma unroll
            for (int i = 0; i < 2; ++i)
                stage16(&sV[cur ^ 1][(i * 256 + wvu * 64) * 8], vg + goffV[i], lane);
        }

        // mask / keylen
        float klv[4], mreg[4][4];
        #pragma unroll
        for (int j = 0; j < 4; ++j) klv[j] = keylen[n * LQ + s0 + j * 16 + r16];
        #pragma unroll
        for (int rr = 0; rr < 4; ++rr) {
            int lrow = l0 + wv * 16 + grp * 4 + rr;
            #pragma unroll
            for (int j = 0; j < 4; ++j)
                mreg[rr][j] = mask[lrow * LQ + s0 + j * 16 + r16];
        }

        // S = Q'.K'^T  (f16 MFMA)
        f32x4 st[4];
        #pragma unroll
        for (int j = 0; j < 4; ++j)
            #pragma unroll
            for (int rr = 0; rr < 4; ++rr) st[j][rr] = 0.f;
        #pragma unroll
        for (int d0 = 0; d0 < 6; ++d0) {
            #pragma unroll
            for (int j = 0; j < 4; ++j) {
                int cc = d0 * 4 + grp;
                int cl = (cc & ~7) | ((cc & 7) ^ swz);
                f16x8 bf = *(const f16x8*)&sK[cur][((j * 16 + r16) * 24 + cl) * 8];
                st[j] = __builtin_amdgcn_mfma_f32_16x16x32_f16(qf[d0], bf, st[j], 0, 0, 0);
            }
        }

        // online softmax (C layout: col=r16+16j, row=grp*4+rr)
        #pragma unroll
        for (int rr = 0; rr < 4; ++rr) {
            float lg[4];
            float mx = -INFINITY;
            #pragma unroll
            for (int j = 0; j < 4; ++j) {
                lg[j] = TEMP * (st[j][rr] + mreg[rr][j] + klv[j]);
                mx = fmaxf(mx, lg[j]);
            }
            #pragma unroll
            for (int d = 1; d < 16; d <<= 1) mx = fmaxf(mx, __shfl_xor(mx, d));
            float mnew  = fmaxf(m_i[rr], mx);
            float alpha = __expf(m_i[rr] - mnew);
            float rs = 0.f;
            #pragma unroll
            for (int j = 0; j < 4; ++j) {
                float p = __expf(lg[j] - mnew);
                rs += p;
                sP[wv][(grp * 4 + rr) * 72 + j * 16 + r16] = (f16)p;
            }
            #pragma unroll
            for (int d = 1; d < 16; d <<= 1) rs += __shfl_xor(rs, d);
            l_i[rr] = l_i[rr] * alpha + rs;
            m_i[rr] = mnew;
            #pragma unroll
            for (int tt = 0; tt < 4; ++tt) O[tt][rr] *= alpha;
        }
        // no barrier: sP round-trip is per-wave; LDS ops in-order per wave

        // O += P.V
        #pragma unroll
        for (int kk = 0; kk < 2; ++kk) {
            f16x8 pa = *(const f16x8*)&sP[wv][r16 * 72 + kk * 32 + grp * 8];
            #pragma unroll
            for (int tt = 0; tt < 4; ++tt) {
                int cc = kk * 4 + grp;
                f16x8 vb = *(const f16x8*)&sV[cur][((tt * 16 + r16) * 8 + (cc ^ swz)) * 8];
                O[tt] = __builtin_amdgcn_mfma_f32_16x16x32_f16(pa, vb, O[tt], 0, 0, 0);
            }
        }
    }

    // epilogue: write unnormalized O and per-row (m, l)
    #pragma unroll
    for (int rr = 0; rr < 4; ++rr) {
        int lrow = l0 + wv * 16 + grp * 4 + rr;
        size_t prow = (size_t)(half * 32 + nh) * LQ + lrow;
        float* op = Op + prow * NE;
        #pragma unroll
        for (int tt = 0; tt < 4; ++tt)
            op[tt * 16 + r16] = O[tt][rr];
        if (r16 == 0) {
            Mp[prow] = m_i[rr];
            Lp[prow] = l_i[rr];
        }
    }
}

// ---------------- merge: combine the two split-K halves (exact) ----------------
__global__ __launch_bounds__(256) void sinattn_merge(
    const float* __restrict__ Op, const float* __restrict__ Mp,
    const float* __restrict__ Lp, float* __restrict__ out)
{
    int idx = blockIdx.x * 256 + threadIdx.x;   // ((n*L+l)*H+h)*E+e
    if (idx >= NB * LQ * NH * NE) return;
    int e = idx & 63;
    int h = (idx >> 6) & 7;
    int t = idx >> 9;
    int l = t % LQ;
    int n = t / LQ;
    int nh = (n << 3) | h;
    int row = nh * LQ + l;
    const int HOFF = 32 * LQ;

    float m0 = Mp[row],        m1 = Mp[HOFF + row];
    float l0 = Lp[row],        l1 = Lp[HOFF + row];
    float mm = fmaxf(m0, m1);
    float a0 = __expf(m0 - mm), a1 = __expf(m1 - mm);
    float denom = l0 * a0 + l1 * a1;
    float o0 = Op[(size_t)row * NE + e];
    float o1 = Op[(size_t)(HOFF + row) * NE + e];
    out[idx] = (o0 * a0 + o1 * a1) / denom;
}

extern "C" void kernel_launch(void* const* d_in, const int* in_sizes, int n_in,
                              void* d_out, int out_size, void* d_ws, size_t ws_size,
                              hipStream_t stream)
{
    const float* Q      = (const float*)d_in[0];
    const float* K      = (const float*)d_in[1];
    const float* V      = (const float*)d_in[2];
    const float* mask   = (const float*)d_in[3];
    const float* keylen = (const float*)d_in[4];
    const float* freqs  = (const float*)d_in[5];
    const float* offs   = (const float*)d_in[6];
    const float* gains  = (const float*)d_in[7];
    const float* gate   = (const float*)d_in[8];
    float* out = (float*)d_out;

    const size_t P = (size_t)NB * NH * LQ * ND;   // 4.72M f16 / plane
    f16* Qf = (f16*)d_ws;
    f16* Kf = Qf + P;
    f16* Vt = Kf + P;                             // 1.57M f16
    float* Op = (float*)(Vt + (size_t)NB * NH * NE * LQ);  // 2*32*768*64 f32
    float* Mp = Op + (size_t)2 * 32 * LQ * NE;
    float* Lp = Mp + (size_t)2 * 32 * LQ;

    sinattn_prepvt<<<1152, 256, 0, stream>>>(Q, K, V, freqs, offs, gains, gate,
                                             Qf, Kf, Vt);
    sinattn_flash<<<768, 256, 0, stream>>>(Qf, Kf, Vt, mask, keylen, Op, Mp, Lp);
    sinattn_merge<<<6144, 256, 0, stream>>>(Op, Mp, Lp, out);
}